// Round 3
// baseline (266.684 us; speedup 1.0000x reference)
//
#include <hip/hip_runtime.h>
#include <hip/hip_bf16.h>

#define SEQ   101
#define BATCH 16384
#define INP   9
#define HID   32
#define NOUT  3
#define NG    128      // 4*HID gate rows
#define HSlin 3232     // HID*SEQ

typedef __attribute__((ext_vector_type(8))) short short8;   // 8 bf16 (4 VGPRs)
typedef __attribute__((ext_vector_type(4))) float f32x4;    // MFMA C/D

__device__ __forceinline__ float fast_sigmoid(float v) {
    return __builtin_amdgcn_rcpf(1.f + __expf(-v));
}
__device__ __forceinline__ float fast_tanh(float v) {
    return 1.f - 2.f * __builtin_amdgcn_rcpf(1.f + __expf(2.f * v));
}
__device__ __forceinline__ unsigned hi16_of(float f) {      // truncate to bf16
    return __float_as_uint(f) >> 16;
}
__device__ __forceinline__ unsigned lo16_of(float f) {      // residual as bf16
    unsigned u = __float_as_uint(f);
    float lo = f - __uint_as_float(u & 0xffff0000u);
    return __float_as_uint(lo) >> 16;
}

// Build per-lane B-fragments for mfma_f32_16x16x32_bf16.
// B-layout: lane l supplies B[k = 8*(l>>4)+j][col = l&15] of tile t (gate = 16t+col).
// xbt combined K-slot map (matches A-side builder in lstm_kernel):
//   k 0..7  : W_ih_hi[g][k]      (pairs x_hi)
//   k 8..15 : W_ih_lo[g][k-8]    (pairs x_hi)
//   k 16..23: W_ih_hi[g][k-16]   (pairs x_lo)
//   k 24    : W_ih_hi[g][8]  k25: W_ih_lo[g][8]  k26: W_ih_hi[g][8]  k27..31: 0
__global__ void prep_kernel(const float* __restrict__ W_ih, const float* __restrict__ W_hh,
                            const float* __restrict__ b_ih, const float* __restrict__ b_hh,
                            unsigned short* __restrict__ bhh_hi, unsigned short* __restrict__ bhh_lo,
                            unsigned short* __restrict__ xbt, float* __restrict__ biasc) {
    int tid = threadIdx.x;            // 0..511 : t = tid>>6, lane = tid&63
    int l = tid & 63;
    int t = tid >> 6;
    int g = 16 * t + (l & 15);
    int kb = 8 * (l >> 4);
    for (int j = 0; j < 8; ++j) {
        int k = kb + j;
        float whh = W_hh[g * HID + k];
        bhh_hi[tid * 8 + j] = (unsigned short)hi16_of(whh);
        bhh_lo[tid * 8 + j] = (unsigned short)lo16_of(whh);
        unsigned v;
        if      (k < 8)   v = hi16_of(W_ih[g * INP + k]);
        else if (k < 16)  v = lo16_of(W_ih[g * INP + (k - 8)]);
        else if (k < 24)  v = hi16_of(W_ih[g * INP + (k - 16)]);
        else if (k == 24) v = hi16_of(W_ih[g * INP + 8]);
        else if (k == 25) v = lo16_of(W_ih[g * INP + 8]);
        else if (k == 26) v = hi16_of(W_ih[g * INP + 8]);
        else              v = 0u;
        xbt[tid * 8 + j] = (unsigned short)v;
    }
    if (tid < NG) biasc[tid] = b_ih[tid] + b_hh[tid];
}

// 2 waves per block, each owning 16 batch rows jointly:
//   wave w computes tiles {2tt+w} = all four gates of hidden units 16w..16w+15.
// h double-buffered in LDS [2][16 rows][33]; one barrier per step (read buf != write buf).
// W_lin fusion + butterfly + atomics alternate by step parity between the waves.
// D-layout: batchrow = 4*(l>>4)+reg, col = l&15. A: row=l&15, k=8*(l>>4)+j. B: k=8*(l>>4)+j, col=l&15.
__global__ __launch_bounds__(128, 1) void lstm_kernel(
    const float* __restrict__ x,                 // [SEQ][BATCH][INP]
    const unsigned short* __restrict__ bhh_hi_g, // [8][64][8]
    const unsigned short* __restrict__ bhh_lo_g,
    const unsigned short* __restrict__ xbt_g,
    const float* __restrict__ biasc,             // [NG]
    const float* __restrict__ W_lin,             // [NOUT][HSlin]
    float* __restrict__ accp)                    // [BATCH][NOUT]+pad accumulators
{
    __shared__ float hb[2][16 * 33];
    const int tid   = threadIdx.x;
    const int lane  = tid & 63;
    const int w     = __builtin_amdgcn_readfirstlane(tid >> 6);  // 0 or 1
    const int row16 = lane & 15;
    const int grp   = lane >> 4;
    const int b0    = blockIdx.x * 16;
    const int b     = b0 + row16;

    for (int i = tid; i < 2 * 16 * 33; i += 128) (&hb[0][0])[i] = 0.f;

    // Preload this wave's B-fragments + bias splats (live across all steps)
    short8 bhi[4], blo[4], xbv[4];
    f32x4 biasv[4];
#pragma unroll
    for (int tt = 0; tt < 4; ++tt) {
        int t = 2 * tt + w;
        bhi[tt] = *reinterpret_cast<const short8*>(bhh_hi_g + (t * 64 + lane) * 8);
        blo[tt] = *reinterpret_cast<const short8*>(bhh_lo_g + (t * 64 + lane) * 8);
        xbv[tt] = *reinterpret_cast<const short8*>(xbt_g    + (t * 64 + lane) * 8);
        float bg = biasc[16 * t + row16];
        biasv[tt][0] = bg; biasv[tt][1] = bg; biasv[tt][2] = bg; biasv[tt][3] = bg;
    }

    // lane-group masks for the packed-x A builder (see xbt map above)
    const bool srcx8 = (lane >= 48);
    const bool hiA   = (lane < 32) || (lane >= 48);      // j<2: groups 0,1,3 take hi
    const bool hiB   = (lane < 32);                      // j>=2: groups 0,1 take hi

    float cst[4] = {0.f, 0.f, 0.f, 0.f};                 // c for (batch 4grp+r, unit row16+16w)
    float xv[9];
    {
        const float* xp = x + (size_t)b * INP;           // s = 0
#pragma unroll
        for (int i = 0; i < 9; ++i) xv[i] = xp[i];
    }

    for (int s = 0; s <= SEQ; ++s) {
        __syncthreads();   // prior step's h writes (and the init) visible

        // h_{s-1}: A-source for step s AND the W_lin operand for step s-1
        const float* hrd = &hb[(s + 1) & 1][row16 * 33 + grp * 8];
        float hv[8];
#pragma unroll
        for (int j = 0; j < 8; ++j) hv[j] = hrd[j];

        const bool duty = (s > 0) && (((s - 1) & 1) == w);

        // Issue W_lin loads early (consumed after the MFMA/activation block)
        float4 wv0a, wv0b, wv1a, wv1b, wv2a, wv2b;
        unsigned rmin = 0; bool low = true;
        if (duty) {
            unsigned blk  = (unsigned)(s - 1) * BATCH + (unsigned)b;
            unsigned r    = blk / 101u;
            unsigned slot = blk - r * 101u;
            rmin = ((unsigned)(s - 1) * BATCH + (unsigned)b0) / 101u;
            low  = (r == rmin);
            const float* wl = W_lin + slot * HID + grp * 8;
            wv0a = *(const float4*)(wl);
            wv0b = *(const float4*)(wl + 4);
            wv1a = *(const float4*)(wl + HSlin);
            wv1b = *(const float4*)(wl + HSlin + 4);
            wv2a = *(const float4*)(wl + 2 * HSlin);
            wv2b = *(const float4*)(wl + 2 * HSlin + 4);
        }

        if (s < SEQ) {
            // ---- packed-x A fragment (branchless, masks precomputed) ----
            short8 xa;
            float xv8 = xv[8];
#pragma unroll
            for (int j = 0; j < 8; ++j) {
                float f = srcx8 ? xv8 : xv[j];
                unsigned u  = __float_as_uint(f);
                unsigned hi = u >> 16;
                float lof   = f - __uint_as_float(u & 0xffff0000u);
                unsigned lo = __float_as_uint(lof) >> 16;
                bool ishi   = (j < 2) ? hiA : hiB;
                unsigned sel = ishi ? hi : lo;
                if (j >= 3) sel = srcx8 ? 0u : sel;
                xa[j] = (short)sel;
            }
            // ---- prefetch next step's x (independent of recurrence) ----
            float xn[9];
            if (s < SEQ - 1) {
                const float* xpn = x + ((size_t)(s + 1) * BATCH + b) * INP;
#pragma unroll
                for (int i = 0; i < 9; ++i) xn[i] = xpn[i];
            }
            // ---- h split-bf16 A fragments ----
            short8 hahi, halo;
#pragma unroll
            for (int j = 0; j < 8; ++j) {
                unsigned u = __float_as_uint(hv[j]);
                hahi[j] = (short)(u >> 16);
                float lof = hv[j] - __uint_as_float(u & 0xffff0000u);
                halo[j] = (short)(__float_as_uint(lof) >> 16);
            }
            // ---- gates: this wave's 4 tiles x 4 MFMA ----
            f32x4 acc[4];
#pragma unroll
            for (int tt = 0; tt < 4; ++tt) {
                acc[tt] = __builtin_amdgcn_mfma_f32_16x16x32_bf16(xa,   xbv[tt], biasv[tt], 0, 0, 0);
                acc[tt] = __builtin_amdgcn_mfma_f32_16x16x32_bf16(hahi, bhi[tt], acc[tt],   0, 0, 0);
                acc[tt] = __builtin_amdgcn_mfma_f32_16x16x32_bf16(hahi, blo[tt], acc[tt],   0, 0, 0);
                acc[tt] = __builtin_amdgcn_mfma_f32_16x16x32_bf16(halo, bhi[tt], acc[tt],   0, 0, 0);
            }
            // ---- activations + h write: lane owns (batch 4grp+r, unit row16+16w) ----
            float* hwp = &hb[s & 1][(grp * 4) * 33 + row16 + 16 * w];
#pragma unroll
            for (int r = 0; r < 4; ++r) {
                float ig = fast_sigmoid(acc[0][r]);
                float fg = fast_sigmoid(acc[1][r]);
                float gg = fast_tanh(acc[2][r]);
                float og = fast_sigmoid(acc[3][r]);
                float cn = fmaf(fg, cst[r], ig * gg);
                cst[r] = cn;
                hwp[r * 33] = og * fast_tanh(cn);
            }
            if (s < SEQ - 1) {
#pragma unroll
                for (int i = 0; i < 9; ++i) xv[i] = xn[i];
            }
        }

        // ---- fused final linear for step s-1 (duty wave only, <=2 output rows) ----
        if (duty) {
            float p0 = wv0a.x*hv[0] + wv0a.y*hv[1] + wv0a.z*hv[2] + wv0a.w*hv[3]
                     + wv0b.x*hv[4] + wv0b.y*hv[5] + wv0b.z*hv[6] + wv0b.w*hv[7];
            float p1 = wv1a.x*hv[0] + wv1a.y*hv[1] + wv1a.z*hv[2] + wv1a.w*hv[3]
                     + wv1b.x*hv[4] + wv1b.y*hv[5] + wv1b.z*hv[6] + wv1b.w*hv[7];
            float p2 = wv2a.x*hv[0] + wv2a.y*hv[1] + wv2a.z*hv[2] + wv2a.w*hv[3]
                     + wv2b.x*hv[4] + wv2b.y*hv[5] + wv2b.z*hv[6] + wv2b.w*hv[7];
            float a0 = low ? p0 : 0.f, a1 = low ? p1 : 0.f, a2 = low ? p2 : 0.f;
            float d0 = low ? 0.f : p0, d1 = low ? 0.f : p1, d2 = low ? 0.f : p2;
#pragma unroll
            for (int m = 1; m < 64; m <<= 1) {
                a0 += __shfl_xor(a0, m); a1 += __shfl_xor(a1, m); a2 += __shfl_xor(a2, m);
                d0 += __shfl_xor(d0, m); d1 += __shfl_xor(d1, m); d2 += __shfl_xor(d2, m);
            }
            if (lane == 0) {
                atomicAdd(&accp[rmin * 3 + 0], a0);
                atomicAdd(&accp[rmin * 3 + 1], a1);
                atomicAdd(&accp[rmin * 3 + 2], a2);
                // rmin+1 may be 16384 only when d==0; accp has pad slots
                atomicAdd(&accp[(rmin + 1u) * 3 + 0], d0);
                atomicAdd(&accp[(rmin + 1u) * 3 + 1], d1);
                atomicAdd(&accp[(rmin + 1u) * 3 + 2], d2);
            }
        }
    }
}

__global__ void finalize_kernel(const float* __restrict__ acc, const float* __restrict__ b_lin,
                                float* __restrict__ out) {
    int i = blockIdx.x * blockDim.x + threadIdx.x;
    if (i < BATCH * NOUT) {
        int r = i / 3;
        int o = i - r * 3;
        out[i] = acc[i] + b_lin[o];
    }
}

extern "C" void kernel_launch(void* const* d_in, const int* in_sizes, int n_in,
                              void* d_out, int out_size, void* d_ws, size_t ws_size,
                              hipStream_t stream) {
    const float* x     = (const float*)d_in[0];
    const float* W_ih  = (const float*)d_in[1];
    const float* W_hh  = (const float*)d_in[2];
    const float* b_ih  = (const float*)d_in[3];
    const float* b_hh  = (const float*)d_in[4];
    const float* W_lin = (const float*)d_in[5];
    const float* b_lin = (const float*)d_in[6];
    float* out = (float*)d_out;

    // ws: acc[49160] f32 | bhh_hi[4096] u16 | bhh_lo[4096] u16 | xbt[4096] u16 | biasc[128] f32
    float* accp = (float*)d_ws;
    unsigned short* bhh_hi = (unsigned short*)(accp + 49160);
    unsigned short* bhh_lo = bhh_hi + 4096;
    unsigned short* xbt    = bhh_lo + 4096;
    float* biasc = (float*)(xbt + 4096);

    hipMemsetAsync(accp, 0, 49160 * sizeof(float), stream);
    hipLaunchKernelGGL(prep_kernel, dim3(1), dim3(512), 0, stream,
                       W_ih, W_hh, b_ih, b_hh, bhh_hi, bhh_lo, xbt, biasc);
    hipLaunchKernelGGL(lstm_kernel, dim3(BATCH / 16), dim3(128), 0, stream,
                       x, bhh_hi, bhh_lo, xbt, biasc, W_lin, accp);
    hipLaunchKernelGGL(finalize_kernel, dim3((BATCH * NOUT + 255) / 256), dim3(256), 0, stream,
                       accp, b_lin, out);
}

// Round 4
// 174.430 us; speedup vs baseline: 1.5289x; 1.5289x over previous
//
#include <hip/hip_runtime.h>
#include <hip/hip_bf16.h>

#define SEQ   101
#define BATCH 16384
#define INP   9
#define HID   32
#define NOUT  3
#define HSlin 3232     // HID*SEQ

typedef __attribute__((ext_vector_type(8))) short short8;   // 8 bf16 (4 VGPRs)
typedef __attribute__((ext_vector_type(4))) float f32x4;    // MFMA C/D

__device__ __forceinline__ unsigned hi16_of(float f) {      // truncate to bf16
    return __float_as_uint(f) >> 16;
}
__device__ __forceinline__ unsigned lo16_of(float f) {      // residual as bf16
    unsigned u = __float_as_uint(f);
    float lo = f - __uint_as_float(u & 0xffff0000u);
    return __float_as_uint(lo) >> 16;
}

// Swapped-operand scheme: gates^T = W * [x|h]^T.
//   A-frag (static): lane supplies A[row=l&15][k=8*(l>>4)+j]; row = gate-in-tile.
//   B-frag (dynamic): lane supplies B[k=8*(l>>4)+j][col=l&15]; col = batch.
//   D: row(gate) = 4*(l>>4)+reg, col(batch) = l&15.
// k-permutation for the h contraction: pi(8g+j) = 4g + (j&3) + 16*(j>>2) —
// chosen so the B-fragment of h is exactly the 8 h values the lane computed
// in its own activations (zero cross-lane movement in the recurrence).
// x k-slot map (same as the verified R2 map, roles swapped):
//   k0-7:  Whi[k]   * xhi[k]     k8-15: Wlo[k-8] * xhi[k-8]
//   k16-23:Whi[k-16]* xlo[k-16]  k24: Whi[8]*xhi[8]  k25: Wlo[8]*xhi[8]
//   k26: Whi[8]*xlo[8]           k27-31: 0
__global__ void prep_kernel(const float* __restrict__ W_ih, const float* __restrict__ W_hh,
                            const float* __restrict__ b_ih, const float* __restrict__ b_hh,
                            unsigned short* __restrict__ whh_hi, unsigned short* __restrict__ whh_lo,
                            unsigned short* __restrict__ wih, float* __restrict__ biasc) {
    int tid = threadIdx.x;            // 0..511 : t = tid>>6, l = tid&63
    int l   = tid & 63;
    int t   = tid >> 6;
    int row = l & 15;                 // gate-in-tile
    int g   = l >> 4;
    int gate = 16 * t + row;
    for (int j = 0; j < 8; ++j) {
        int u = 4 * g + (j & 3) + 16 * (j >> 2);     // pi(8g+j)
        float whh = W_hh[gate * HID + u];
        whh_hi[tid * 8 + j] = (unsigned short)hi16_of(whh);
        whh_lo[tid * 8 + j] = (unsigned short)lo16_of(whh);
        int k = 8 * g + j;
        const float* Wr = W_ih + gate * INP;
        unsigned v;
        if      (k < 8)   v = hi16_of(Wr[k]);
        else if (k < 16)  v = lo16_of(Wr[k - 8]);
        else if (k < 24)  v = hi16_of(Wr[k - 16]);
        else if (k == 24) v = hi16_of(Wr[8]);
        else if (k == 25) v = lo16_of(Wr[8]);
        else if (k == 26) v = hi16_of(Wr[8]);
        else              v = 0u;
        wih[tid * 8 + j] = (unsigned short)v;
    }
    if (tid < 4 * HID) biasc[tid] = b_ih[tid] + b_hh[tid];
}

// Cross-lane reduce of the 3 W_lin partials -> <=2 output rows, 6 atomics.
__device__ __forceinline__ void reduce_emit(float p0, float p1, float p2,
                                            bool low, unsigned rmin,
                                            float* __restrict__ accp, int lane) {
    // reduce over the 4 grps (same batch col): lanes xor 16, 32
    p0 += __shfl_xor(p0, 16); p1 += __shfl_xor(p1, 16); p2 += __shfl_xor(p2, 16);
    p0 += __shfl_xor(p0, 32); p1 += __shfl_xor(p1, 32); p2 += __shfl_xor(p2, 32);
    // split by output row (col-dependent), then reduce over the 16 cols
    float a0 = low ? p0 : 0.f, a1 = low ? p1 : 0.f, a2 = low ? p2 : 0.f;
    float d0 = low ? 0.f : p0, d1 = low ? 0.f : p1, d2 = low ? 0.f : p2;
#pragma unroll
    for (int m = 1; m < 16; m <<= 1) {
        a0 += __shfl_xor(a0, m); a1 += __shfl_xor(a1, m); a2 += __shfl_xor(a2, m);
        d0 += __shfl_xor(d0, m); d1 += __shfl_xor(d1, m); d2 += __shfl_xor(d2, m);
    }
    int anyhi = __any(!low);
    if (lane == 0) {
        atomicAdd(&accp[rmin * 3 + 0], a0);
        atomicAdd(&accp[rmin * 3 + 1], a1);
        atomicAdd(&accp[rmin * 3 + 2], a2);
        if (anyhi) {
            atomicAdd(&accp[(rmin + 1u) * 3 + 0], d0);
            atomicAdd(&accp[(rmin + 1u) * 3 + 1], d1);
            atomicAdd(&accp[(rmin + 1u) * 3 + 2], d2);
        }
    }
}

// One wave per 16 batch rows; recurrence fully register-resident (no LDS).
__global__ __launch_bounds__(64, 1) void lstm_kernel(
    const float* __restrict__ x,                 // [SEQ][BATCH][INP]
    const unsigned short* __restrict__ whh_hi_g, // [8][64][8] A-frags
    const unsigned short* __restrict__ whh_lo_g,
    const unsigned short* __restrict__ wih_g,
    const float* __restrict__ biasc,             // [4H]
    const float* __restrict__ W_lin,             // [NOUT][HSlin]
    float* __restrict__ accp)                    // [BATCH+1][NOUT] accumulators
{
    const int lane = threadIdx.x;
    const int c    = lane & 15;        // batch col
    const int g    = lane >> 4;
    const int b0   = blockIdx.x * 16;
    const int b    = b0 + c;

    // Static A-fragments + per-lane bias quads (live across all steps)
    short8 whi[8], wlo[8], xw[8];
    f32x4 biasv[8];
#pragma unroll
    for (int t = 0; t < 8; ++t) {
        whi[t] = *reinterpret_cast<const short8*>(whh_hi_g + (t * 64 + lane) * 8);
        wlo[t] = *reinterpret_cast<const short8*>(whh_lo_g + (t * 64 + lane) * 8);
        xw[t]  = *reinterpret_cast<const short8*>(wih_g    + (t * 64 + lane) * 8);
        biasv[t] = *reinterpret_cast<const f32x4*>(biasc + 16 * t + 4 * g);
    }

    // lane-group masks for the packed-x B builder (k-map above)
    const bool srcx8 = (lane >= 48);
    const bool hiA   = (lane < 32) || (lane >= 48);      // j<2: grps 0,1,3 take hi
    const bool hiB   = (lane < 32);                      // j>=2: grps 0,1 take hi

    float cst[2][4] = {{0.f,0.f,0.f,0.f},{0.f,0.f,0.f,0.f}};
    float hlc[2][4] = {{0.f,0.f,0.f,0.f},{0.f,0.f,0.f,0.f}};  // h[half][r]: unit 16*half+4g+r, batch c
    float xv[9];
    {
        const float* xp = x + (size_t)b * INP;           // s = 0
#pragma unroll
        for (int i = 0; i < 9; ++i) xv[i] = xp[i];
    }

    // staged previous-step W_lin partials
    float pp0 = 0.f, pp1 = 0.f, pp2 = 0.f;
    unsigned prmin = 0; bool plow = true;

    for (int s = 0; s < SEQ; ++s) {
        // (0) this step's W_lin weights (consumed after activations)
        unsigned blk  = (unsigned)s * BATCH + (unsigned)b;
        unsigned r    = blk / 101u;
        unsigned slot = blk - r * 101u;
        unsigned rmin = ((unsigned)s * BATCH + (unsigned)b0) / 101u;
        bool     low  = (r == rmin);
        const float* wl = W_lin + slot * HID + 4 * g;
        float4 w0a = *(const float4*)(wl);
        float4 w0b = *(const float4*)(wl + 16);
        float4 w1a = *(const float4*)(wl + HSlin);
        float4 w1b = *(const float4*)(wl + HSlin + 16);
        float4 w2a = *(const float4*)(wl + 2 * HSlin);
        float4 w2b = *(const float4*)(wl + 2 * HSlin + 16);

        // (1) packed-x B fragment (branchless)
        short8 xa;
        {
            float xv8 = xv[8];
#pragma unroll
            for (int j = 0; j < 8; ++j) {
                float f = srcx8 ? xv8 : xv[j];
                unsigned u  = __float_as_uint(f);
                unsigned hi = u >> 16;
                float lof   = f - __uint_as_float(u & 0xffff0000u);
                unsigned lo = __float_as_uint(lof) >> 16;
                bool ishi   = (j < 2) ? hiA : hiB;
                unsigned sel = ishi ? hi : lo;
                if (j >= 3) sel = srcx8 ? 0u : sel;
                xa[j] = (short)sel;
            }
        }
        // (2) h B-fragment = own h, split hi/lo (zero cross-lane movement)
        short8 bh, bl;
#pragma unroll
        for (int j = 0; j < 8; ++j) {
            float h = hlc[j >> 2][j & 3];
            unsigned u = __float_as_uint(h);
            bh[j] = (short)(u >> 16);
            float lof = h - __uint_as_float(u & 0xffff0000u);
            bl[j] = (short)(__float_as_uint(lof) >> 16);
        }
        // (3) gates^T: 8 tiles x 4 MFMA (A = static weight frags)
        f32x4 acc[8];
#pragma unroll
        for (int t = 0; t < 8; ++t) {
            acc[t] = __builtin_amdgcn_mfma_f32_16x16x32_bf16(xw[t],  xa, biasv[t], 0, 0, 0);
            acc[t] = __builtin_amdgcn_mfma_f32_16x16x32_bf16(whi[t], bh, acc[t],   0, 0, 0);
            acc[t] = __builtin_amdgcn_mfma_f32_16x16x32_bf16(wlo[t], bh, acc[t],   0, 0, 0);
            acc[t] = __builtin_amdgcn_mfma_f32_16x16x32_bf16(whi[t], bl, acc[t],   0, 0, 0);
        }
        // (4) previous step's butterfly + atomics — hides under MFMA latency
        if (s > 0) reduce_emit(pp0, pp1, pp2, plow, prmin, accp, lane);

        // (5) prefetch next step's x
        float xn[9];
        if (s < SEQ - 1) {
            const float* xpn = x + ((size_t)(s + 1) * BATCH + b) * INP;
#pragma unroll
            for (int i = 0; i < 9; ++i) xn[i] = xpn[i];
        }

        // (6) activations: lane holds i,f,g,o of its 8 (unit,batch) pairs.
        //     sigma(i)*tanh(g) = (1-eg) / ((1+ei)*(1+eg)), eg = e^{-2g}, ei = e^{-i}
#pragma unroll
        for (int half = 0; half < 2; ++half) {
#pragma unroll
            for (int q = 0; q < 4; ++q) {
                float iv = acc[0 + half][q], fv = acc[2 + half][q];
                float gv = acc[4 + half][q], ov = acc[6 + half][q];
                float ef = __expf(-fv);
                float sf = __builtin_amdgcn_rcpf(1.f + ef);          // sigma(f)
                float ei = __expf(-iv);
                float eg = __expf(-2.f * gv);
                float st = (1.f - eg) * __builtin_amdgcn_rcpf((1.f + ei) * (1.f + eg));
                float cn = fmaf(sf, cst[half][q], st);
                cst[half][q] = cn;
                float eo = __expf(-ov);
                float ec = __expf(-2.f * cn);
                hlc[half][q] = (1.f - ec) * __builtin_amdgcn_rcpf((1.f + eo) * (1.f + ec));
            }
        }
        if (s < SEQ - 1) {
#pragma unroll
            for (int i = 0; i < 9; ++i) xv[i] = xn[i];
        }

        // (7) this step's W_lin partials (units 4g+q <- half0, 16+4g+q <- half1)
        pp0 = w0a.x*hlc[0][0] + w0a.y*hlc[0][1] + w0a.z*hlc[0][2] + w0a.w*hlc[0][3]
            + w0b.x*hlc[1][0] + w0b.y*hlc[1][1] + w0b.z*hlc[1][2] + w0b.w*hlc[1][3];
        pp1 = w1a.x*hlc[0][0] + w1a.y*hlc[0][1] + w1a.z*hlc[0][2] + w1a.w*hlc[0][3]
            + w1b.x*hlc[1][0] + w1b.y*hlc[1][1] + w1b.z*hlc[1][2] + w1b.w*hlc[1][3];
        pp2 = w2a.x*hlc[0][0] + w2a.y*hlc[0][1] + w2a.z*hlc[0][2] + w2a.w*hlc[0][3]
            + w2b.x*hlc[1][0] + w2b.y*hlc[1][1] + w2b.z*hlc[1][2] + w2b.w*hlc[1][3];
        prmin = rmin; plow = low;
    }
    // epilogue: butterfly for s = SEQ-1
    reduce_emit(pp0, pp1, pp2, plow, prmin, accp, lane);
}

__global__ void finalize_kernel(const float* __restrict__ acc, const float* __restrict__ b_lin,
                                float* __restrict__ out) {
    int i = blockIdx.x * blockDim.x + threadIdx.x;
    if (i < BATCH * NOUT) {
        int r = i / 3;
        int o = i - r * 3;
        out[i] = acc[i] + b_lin[o];
    }
}

extern "C" void kernel_launch(void* const* d_in, const int* in_sizes, int n_in,
                              void* d_out, int out_size, void* d_ws, size_t ws_size,
                              hipStream_t stream) {
    const float* x     = (const float*)d_in[0];
    const float* W_ih  = (const float*)d_in[1];
    const float* W_hh  = (const float*)d_in[2];
    const float* b_ih  = (const float*)d_in[3];
    const float* b_hh  = (const float*)d_in[4];
    const float* W_lin = (const float*)d_in[5];
    const float* b_lin = (const float*)d_in[6];
    float* out = (float*)d_out;

    // ws: acc[49160] f32 | whh_hi[4096] u16 | whh_lo[4096] u16 | wih[4096] u16 | biasc[128] f32
    float* accp = (float*)d_ws;
    unsigned short* whh_hi = (unsigned short*)(accp + 49160);
    unsigned short* whh_lo = whh_hi + 4096;
    unsigned short* wih    = whh_lo + 4096;
    float* biasc = (float*)(wih + 4096);

    hipMemsetAsync(accp, 0, 49160 * sizeof(float), stream);
    hipLaunchKernelGGL(prep_kernel, dim3(1), dim3(512), 0, stream,
                       W_ih, W_hh, b_ih, b_hh, whh_hi, whh_lo, wih, biasc);
    hipLaunchKernelGGL(lstm_kernel, dim3(BATCH / 16), dim3(64), 0, stream,
                       x, whh_hi, whh_lo, wih, biasc, W_lin, accp);
    hipLaunchKernelGGL(finalize_kernel, dim3((BATCH * NOUT + 255) / 256), dim3(256), 0, stream,
                       accp, b_lin, out);
}